// Round 5
// baseline (294.868 us; speedup 1.0000x reference)
//
#include <hip/hip_runtime.h>
#include <hip/hip_fp16.h>
#include <hip/hip_cooperative_groups.h>
#include <math.h>

namespace cg = cooperative_groups;

#define SEQ   4096
#define DIM   128
#define UDIM  64
#define BATCH 4
#define BS    (BATCH*SEQ)
#define NT    (SEQ/64)   // 64 key tiles
#define NSPLIT 4         // 2048 wave-units = 256 blocks x 8 waves exactly

typedef _Float16 h8 __attribute__((ext_vector_type(8)));
typedef _Float16 h4 __attribute__((ext_vector_type(4)));
typedef _Float16 h2 __attribute__((ext_vector_type(2)));
typedef float    f4 __attribute__((ext_vector_type(4)));

#define MFMA_K32(a,b,c) __builtin_amdgcn_mfma_f32_16x16x32_f16((a),(b),(c),0,0,0)

__device__ __forceinline__ h2 pk2(float a, float b) {
  return __builtin_bit_cast(h2, __builtin_amdgcn_cvt_pkrtz(a, b));
}
__device__ __forceinline__ float fexp2(float x) {
#if __has_builtin(__builtin_amdgcn_exp2f)
  return __builtin_amdgcn_exp2f(x);
#else
  return exp2f(x);
#endif
}

#define WT_STRIDE 272   // W^T row stride (136 halves): conflict-free b128
#define KB_STRIDE 144
#define L2E 1.44269504088896f

// R15: ONE cooperative kernel, 3 phases separated by grid.sync().
// Rationale: 5 structural changes to flash's inner loop were all null ->
// the 110us lives between kernels (launch gaps, dispatch serialization),
// not inside them. Fusing also makes our code visible in rocprof top-5.
//
// Layouts (unchanged):
//  kswz: slot(mt*2+ks)*1024B + lane*16B : lane(quad,n) = K[kb*16+n][ks*32+quad*8..]
//  vswz (K32 A-frag): slot(hh*4+ut): lane = V^T[16ut+n][tile*64+32hh+8quad+j]
//  q pre-scaled by log2(e).

__global__ __launch_bounds__(512, 2) void fused_attn(
    const float* __restrict__ x,
    const float* __restrict__ Wq, const float* __restrict__ bq,
    const float* __restrict__ Wk, const float* __restrict__ bk,
    const float* __restrict__ Wv, const float* __restrict__ bv,
    _Float16* __restrict__ qf, _Float16* __restrict__ kswz,
    _Float16* __restrict__ vswz,
    _Float16* __restrict__ opart, float* __restrict__ Mp,
    float* __restrict__ Lp, float* __restrict__ out)
{
  cg::grid_group grid = cg::this_grid();
  const int tid  = threadIdx.x;
  const int lane = tid & 63, wid = tid >> 6;
  const int n = lane & 15, quad = lane >> 4;

  __shared__ __align__(16) char wlds[3][UDIM * WT_STRIDE];   // 52224 B
  __shared__ __align__(16) char kbnc[4 * 16 * KB_STRIDE];    //  9216 B

  // ================= phase 1: fused qkv projection =================
  {
    const int r0 = blockIdx.x * 64;

    #pragma unroll
    for (int p = 0; p < 3; ++p) {
      const float* __restrict__ W = (p == 0) ? Wq : ((p == 1) ? Wk : Wv);
      #pragma unroll
      for (int i = 0; i < 4; ++i) {            // 512 threads: 4 iters cover 2048
        const int idx = i*512 + tid;
        const int nn  = idx & 63;
        const int k4  = (idx >> 6) * 4;
        const float w0 = W[(k4+0)*UDIM + nn];
        const float w1 = W[(k4+1)*UDIM + nn];
        const float w2 = W[(k4+2)*UDIM + nn];
        const float w3 = W[(k4+3)*UDIM + nn];
        int2 wd;
        wd.x = __builtin_bit_cast(int, pk2(w0, w1));
        wd.y = __builtin_bit_cast(int, pk2(w2, w3));
        *(int2*)(wlds[p] + nn*WT_STRIDE + k4*2) = wd;
      }
    }

    const int g    = wid & 3;      // 16-row group
    const int half = wid >> 2;     // 0: Q+K, 1: V
    const int row  = r0 + g*16 + n;
    h8 xa[4];
    #pragma unroll
    for (int ks = 0; ks < 4; ++ks) {
      const float* xp = x + (size_t)row*DIM + ks*32 + quad*8;
      const f4 a = *(const f4*)xp, bb2 = *(const f4*)(xp + 4);
      int4 pkd;
      pkd.x = __builtin_bit_cast(int, pk2(a[0], a[1]));
      pkd.y = __builtin_bit_cast(int, pk2(a[2], a[3]));
      pkd.z = __builtin_bit_cast(int, pk2(bb2[0], bb2[1]));
      pkd.w = __builtin_bit_cast(int, pk2(bb2[2], bb2[3]));
      xa[ks] = __builtin_bit_cast(h8, pkd);
    }
    __syncthreads();

    const int b  = r0 / SEQ;
    const int kb = ((r0 % SEQ) >> 4) + g;
    const int vt = (r0 % SEQ) >> 6;

    auto gemm16 = [&](const char* wp, const float* bias, f4* acc) {
      #pragma unroll
      for (int nt = 0; nt < 4; ++nt) acc[nt] = (f4){0.f,0.f,0.f,0.f};
      #pragma unroll
      for (int ks = 0; ks < 4; ++ks)
        #pragma unroll
        for (int nt = 0; nt < 4; ++nt) {
          const h8 wf = *(const h8*)(wp + (nt*16 + n)*WT_STRIDE + (ks*32 + quad*8)*2);
          acc[nt] = MFMA_K32(xa[ks], wf, acc[nt]);
        }
      #pragma unroll
      for (int nt = 0; nt < 4; ++nt) {
        const float bb = bias[nt*16 + n];
        #pragma unroll
        for (int r = 0; r < 4; ++r) acc[nt][r] += bb;
      }
    };

    if (half == 0) {
      { // ---- Q ----
        f4 acc[4];
        gemm16(wlds[0], bq, acc);
        #pragma unroll
        for (int nt = 0; nt < 4; ++nt)
          #pragma unroll
          for (int r = 0; r < 4; ++r) acc[nt][r] *= L2E;
        const int par = lane & 1;
        const unsigned sel = par ? 0x03020706u : 0x05040100u;
        #pragma unroll
        for (int nt = 0; nt < 4; ++nt)
          #pragma unroll
          for (int pp = 0; pp < 2; ++pp) {
            const int r = 2*pp;
            unsigned A  = __builtin_bit_cast(unsigned, pk2(acc[nt][r], acc[nt][r+1]));
            unsigned Bs = (unsigned)__builtin_amdgcn_mov_dpp((int)A, 0xB1, 0xF, 0xF, true);
            unsigned w  = __builtin_amdgcn_perm(Bs, A, sel);
            const int orow = r0 + g*16 + 4*quad + r + par;
            const int ocol = nt*16 + n - par;
            *(unsigned*)((char*)qf + ((size_t)orow*UDIM + ocol)*2) = w;
          }
      }
      { // ---- K ----
        f4 acc[4];
        gemm16(wlds[1], bk, acc);
        char* base = kbnc + g*(16*KB_STRIDE);
        #pragma unroll
        for (int nt = 0; nt < 4; ++nt)
          #pragma unroll
          for (int r = 0; r < 4; ++r)
            *(_Float16*)(base + (4*quad + r)*KB_STRIDE + (nt*16 + n)*2) =
                (_Float16)acc[nt][r];
        _Float16* kdst = kswz + (size_t)b*SEQ*UDIM;
        #pragma unroll
        for (int ks = 0; ks < 2; ++ks) {
          const h8 f = *(const h8*)(base + n*KB_STRIDE + ks*64 + quad*16);
          *(h8*)(kdst + ((size_t)(kb*2 + ks)*64 + lane)*8) = f;
        }
      }
    } else {
      // ---- V (K32 A-frag layout) ----
      f4 acc[4];
      gemm16(wlds[2], bv, acc);
      _Float16* vdst = vswz + (size_t)b*SEQ*UDIM + (size_t)vt*4096;
      const int hh = g >> 1;
      const int qp = 2*(g & 1) + (quad >> 1);
      const int jb = (quad & 1) * 4;
      #pragma unroll
      for (int nt = 0; nt < 4; ++nt) {
        int2 t;
        t.x = __builtin_bit_cast(int, pk2(acc[nt][0], acc[nt][1]));
        t.y = __builtin_bit_cast(int, pk2(acc[nt][2], acc[nt][3]));
        *(int2*)(vdst + (hh*4 + nt)*512 + (16*qp + n)*8 + jb) = t;
      }
    }
  }

  __threadfence();
  grid.sync();

  // ================= phase 2: barrier-free flash (R13 body) =================
  {
    const int Wg  = blockIdx.x*8 + wid;      // 0..2047
    const int o   = Wg >> 2;                 // unit of 4 waves, 0..511
    const int qt  = o & 31;
    const int fb  = (o >> 5) & 3;
    const int sp  = o >> 7;                  // 0..3
    const int kt0 = sp * (NT/NSPLIT);
    const int kt1 = kt0 + (NT/NSPLIT);
    const int qbase = qt*128 + (Wg & 3)*32;

    const _Float16* __restrict__ qb = qf + (size_t)fb*SEQ*UDIM;
    const _Float16* kpl = kswz + (size_t)fb*SEQ*UDIM + (size_t)kt0*4096 + lane*8;
    const _Float16* kph = kpl + 2048;
    const _Float16* vpl = vswz + (size_t)fb*SEQ*UDIM + (size_t)kt0*4096 + lane*8;
    const _Float16* vph = vpl + 2048;

    h8 qB[2][2];
    #pragma unroll
    for (int nt = 0; nt < 2; ++nt)
      #pragma unroll
      for (int ks = 0; ks < 2; ++ks)
        qB[nt][ks] = *(const h8*)(qb + (size_t)(qbase + nt*16 + n)*UDIM + ks*32 + quad*8);

    f4 O[4][2], Ol[2];
    #pragma unroll
    for (int ut = 0; ut < 4; ++ut)
      #pragma unroll
      for (int nt = 0; nt < 2; ++nt) O[ut][nt] = (f4){0.f,0.f,0.f,0.f};
    Ol[0] = (f4){0.f,0.f,0.f,0.f};
    Ol[1] = (f4){0.f,0.f,0.f,0.f};

    float M[2] = {-1e30f, -1e30f};

    h8 ones8;
    { const _Float16 one = (_Float16)1.0f;
      #pragma unroll
      for (int i = 0; i < 8; ++i) ones8[i] = one; }

    const int alo4 = ((32*((lane >> 4) & 1) + (lane & 15)) << 2);
    const int ahi4 = alo4 + 64;
    const bool qlo = (lane < 32);

    h8 ka[4][2];
    ka[0][0] = *(const h8*)(kpl);        ka[0][1] = *(const h8*)(kpl +  512);
    ka[1][0] = *(const h8*)(kpl + 1024); ka[1][1] = *(const h8*)(kpl + 1536);
    ka[2][0] = *(const h8*)(kph);        ka[2][1] = *(const h8*)(kph +  512);
    ka[3][0] = *(const h8*)(kph + 1024); ka[3][1] = *(const h8*)(kph + 1536);

    for (int t = kt0; t < kt1; ++t) {
      h8 va0[4];
      va0[0] = *(const h8*)(vpl);        va0[1] = *(const h8*)(vpl +  512);
      va0[2] = *(const h8*)(vpl + 1024); va0[3] = *(const h8*)(vpl + 1536);

      f4 S[4][2];
      #pragma unroll
      for (int mt = 0; mt < 4; ++mt)
        #pragma unroll
        for (int nt = 0; nt < 2; ++nt) S[mt][nt] = (f4){0.f,0.f,0.f,0.f};
      #pragma unroll
      for (int ks = 0; ks < 2; ++ks)
        #pragma unroll
        for (int mt = 0; mt < 4; ++mt)
          #pragma unroll
          for (int nt = 0; nt < 2; ++nt)
            S[mt][nt] = MFMA_K32(ka[mt][ks], qB[nt][ks], S[mt][nt]);

      if (t + 1 < kt1) {
        kpl += 4096; kph += 4096;
        ka[0][0] = *(const h8*)(kpl);        ka[0][1] = *(const h8*)(kpl +  512);
        ka[1][0] = *(const h8*)(kpl + 1024); ka[1][1] = *(const h8*)(kpl + 1536);
        ka[2][0] = *(const h8*)(kph);        ka[2][1] = *(const h8*)(kph +  512);
        ka[3][0] = *(const h8*)(kph + 1024); ka[3][1] = *(const h8*)(kph + 1536);
      }

      float mn[2];
      #pragma unroll
      for (int nt = 0; nt < 2; ++nt) {
        float m0 = fmaxf(fmaxf(S[0][nt][0], S[0][nt][1]), fmaxf(S[0][nt][2], S[0][nt][3]));
        float m1 = fmaxf(fmaxf(S[1][nt][0], S[1][nt][1]), fmaxf(S[1][nt][2], S[1][nt][3]));
        float m2 = fmaxf(fmaxf(S[2][nt][0], S[2][nt][1]), fmaxf(S[2][nt][2], S[2][nt][3]));
        float m3 = fmaxf(fmaxf(S[3][nt][0], S[3][nt][1]), fmaxf(S[3][nt][2], S[3][nt][3]));
        float rm = fmaxf(fmaxf(m0, m1), fmaxf(m2, m3));
        rm = fmaxf(rm, __shfl_xor(rm, 16));
        rm = fmaxf(rm, __shfl_xor(rm, 32));
        mn[nt] = fmaxf(M[nt], rm);
      }

      const bool nochange = (mn[0] == M[0]) && (mn[1] == M[1]);
      if (!__all(nochange)) {
        #pragma unroll
        for (int nt = 0; nt < 2; ++nt) {
          const float alpha = fexp2(M[nt] - mn[nt]);
          #pragma unroll
          for (int ut = 0; ut < 4; ++ut)
            #pragma unroll
            for (int r = 0; r < 4; ++r) O[ut][nt][r] *= alpha;
          #pragma unroll
          for (int r = 0; r < 4; ++r) Ol[nt][r] *= alpha;
        }
      }
      M[0] = mn[0]; M[1] = mn[1];

      h4 pB[4][2];
      #pragma unroll
      for (int mt = 0; mt < 4; ++mt)
        #pragma unroll
        for (int nt = 0; nt < 2; ++nt) {
          #pragma unroll
          for (int r = 0; r < 4; ++r)
            S[mt][nt][r] = fexp2(S[mt][nt][r] - mn[nt]);
          int2 tt;
          tt.x = __builtin_bit_cast(int, pk2(S[mt][nt][0], S[mt][nt][1]));
          tt.y = __builtin_bit_cast(int, pk2(S[mt][nt][2], S[mt][nt][3]));
          pB[mt][nt] = __builtin_bit_cast(h4, tt);
        }

      h8 pb32a[2];
      #pragma unroll
      for (int nt = 0; nt < 2; ++nt) {
        const int2 X = __builtin_bit_cast(int2, pB[0][nt]);
        const int2 Y = __builtin_bit_cast(int2, pB[1][nt]);
        int4 oo;
        { int a0 = __builtin_amdgcn_ds_bpermute(alo4, X.x);
          int b0 = __builtin_amdgcn_ds_bpermute(alo4, Y.x);
          int a1 = __builtin_amdgcn_ds_bpermute(alo4, X.y);
          int b1 = __builtin_amdgcn_ds_bpermute(alo4, Y.y);
          int a2 = __builtin_amdgcn_ds_bpermute(ahi4, X.x);
          int b2 = __builtin_amdgcn_ds_bpermute(ahi4, Y.x);
          int a3 = __builtin_amdgcn_ds_bpermute(ahi4, X.y);
          int b3 = __builtin_amdgcn_ds_bpermute(ahi4, Y.y);
          oo.x = qlo ? a0 : b0; oo.y = qlo ? a1 : b1;
          oo.z = qlo ? a2 : b2; oo.w = qlo ? a3 : b3; }
        pb32a[nt] = __builtin_bit_cast(h8, oo);
      }

      h8 va1[4];
      va1[0] = *(const h8*)(vph);        va1[1] = *(const h8*)(vph +  512);
      va1[2] = *(const h8*)(vph + 1024); va1[3] = *(const h8*)(vph + 1536);

      #pragma unroll
      for (int ut = 0; ut < 4; ++ut)
        #pragma unroll
        for (int nt = 0; nt < 2; ++nt)
          O[ut][nt] = MFMA_K32(va0[ut], pb32a[nt], O[ut][nt]);
      #pragma unroll
      for (int nt = 0; nt < 2; ++nt)
        Ol[nt] = MFMA_K32(ones8, pb32a[nt], Ol[nt]);

      h8 pb32b[2];
      #pragma unroll
      for (int nt = 0; nt < 2; ++nt) {
        const int2 X = __builtin_bit_cast(int2, pB[2][nt]);
        const int2 Y = __builtin_bit_cast(int2, pB[3][nt]);
        int4 oo;
        { int a0 = __builtin_amdgcn_ds_bpermute(alo4, X.x);
          int b0 = __builtin_amdgcn_ds_bpermute(alo4, Y.x);
          int a1 = __builtin_amdgcn_ds_bpermute(alo4, X.y);
          int b1 = __builtin_amdgcn_ds_bpermute(alo4, Y.y);
          int a2 = __builtin_amdgcn_ds_bpermute(ahi4, X.x);
          int b2 = __builtin_amdgcn_ds_bpermute(ahi4, Y.x);
          int a3 = __builtin_amdgcn_ds_bpermute(ahi4, X.y);
          int b3 = __builtin_amdgcn_ds_bpermute(ahi4, Y.y);
          oo.x = qlo ? a0 : b0; oo.y = qlo ? a1 : b1;
          oo.z = qlo ? a2 : b2; oo.w = qlo ? a3 : b3; }
        pb32b[nt] = __builtin_bit_cast(h8, oo);
      }

      #pragma unroll
      for (int ut = 0; ut < 4; ++ut)
        #pragma unroll
        for (int nt = 0; nt < 2; ++nt)
          O[ut][nt] = MFMA_K32(va1[ut], pb32b[nt], O[ut][nt]);
      #pragma unroll
      for (int nt = 0; nt < 2; ++nt)
        Ol[nt] = MFMA_K32(ones8, pb32b[nt], Ol[nt]);

      vpl += 4096; vph += 4096;
    }

    const size_t rowg = (size_t)sp*BS + (size_t)fb*SEQ + qbase;
    #pragma unroll
    for (int nt = 0; nt < 2; ++nt) {
      char* __restrict__ orow = (char*)(opart + (rowg + nt*16 + n)*UDIM);
      #pragma unroll
      for (int ut = 0; ut < 4; ++ut)
        #pragma unroll
        for (int p = 0; p < 2; ++p)
          *(unsigned*)(orow + (ut*16 + quad*4 + 2*p)*2) =
              __builtin_bit_cast(unsigned, pk2(O[ut][nt][2*p], O[ut][nt][2*p+1]));
      if (quad == 0) {
        Mp[rowg + nt*16 + n] = M[nt];        // log2 domain
        Lp[rowg + nt*16 + n] = Ol[nt][0];
      }
    }
  }

  __threadfence();
  grid.sync();

  // ================= phase 3: merge key-split partials =================
  {
    #pragma unroll
    for (int it = 0; it < 2; ++it) {
      const int task = it*(256*512) + blockIdx.x*512 + tid;   // 262144 tasks
      const int row  = task >> 4;
      const int u4   = (task & 15) * 4;
      float Mm = -1e30f;
      #pragma unroll
      for (int s = 0; s < NSPLIT; ++s) Mm = fmaxf(Mm, Mp[(size_t)s*BS + row]);
      f4 num = (f4){0.f,0.f,0.f,0.f};
      float den = 0.f;
      #pragma unroll
      for (int s = 0; s < NSPLIT; ++s) {
        const float w = fexp2(Mp[(size_t)s*BS + row] - Mm);
        den += w * Lp[(size_t)s*BS + row];
        const h4 op = *(const h4*)(opart + ((size_t)s*BS + row)*UDIM + u4);
        #pragma unroll
        for (int i = 0; i < 4; ++i) num[i] += w * (float)op[i];
      }
      const float dinv = 1.f / den;
      *(f4*)(out + (size_t)row*UDIM + u4) = num * dinv;
    }
  }
}

extern "C" void kernel_launch(void* const* d_in, const int* in_sizes, int n_in,
                              void* d_out, int out_size, void* d_ws, size_t ws_size,
                              hipStream_t stream) {
  (void)in_sizes; (void)n_in; (void)out_size; (void)ws_size;
  const float* x  = (const float*)d_in[0];
  const float* Wq = (const float*)d_in[1];
  const float* bq = (const float*)d_in[2];
  const float* Wk = (const float*)d_in[3];
  const float* bk = (const float*)d_in[4];
  const float* Wv = (const float*)d_in[5];
  const float* bv = (const float*)d_in[6];
  float* out = (float*)d_out;

  char* ws = (char*)d_ws;
  const size_t fBytes = (size_t)BS * UDIM * 2;

  _Float16* qf    = (_Float16*)(ws);
  _Float16* kswz  = (_Float16*)(ws + fBytes);
  _Float16* vswz  = (_Float16*)(ws + 2*fBytes);
  float*    Mp    = (float*)(ws + 3*fBytes);
  float*    Lp    = (float*)(ws + 3*fBytes + (size_t)NSPLIT*BS*4);
  _Float16* opart = (_Float16*)(ws + 3*fBytes + (size_t)NSPLIT*BS*8);

  void* kargs[] = {
    (void*)&x, (void*)&Wq, (void*)&bq, (void*)&Wk, (void*)&bk,
    (void*)&Wv, (void*)&bv, (void*)&qf, (void*)&kswz, (void*)&vswz,
    (void*)&opart, (void*)&Mp, (void*)&Lp, (void*)&out
  };
  hipLaunchCooperativeKernel((const void*)fused_attn, dim3(256), dim3(512),
                             kargs, 0, stream);
}

// Round 7
// 232.753 us; speedup vs baseline: 1.2669x; 1.2669x over previous
//
#include <hip/hip_runtime.h>
#include <hip/hip_fp16.h>
#include <math.h>

#define SEQ   4096
#define DIM   128
#define UDIM  64
#define BATCH 4
#define BS    (BATCH*SEQ)
#define NT    (SEQ/64)   // 64 key tiles
#define NSPLIT 6         // 768 blocks = 3072 waves = exactly one resident pass

typedef _Float16 h8 __attribute__((ext_vector_type(8)));
typedef _Float16 h4 __attribute__((ext_vector_type(4)));
typedef _Float16 h2 __attribute__((ext_vector_type(2)));
typedef float    f4 __attribute__((ext_vector_type(4)));

#define MFMA_K32(a,b,c) __builtin_amdgcn_mfma_f32_16x16x32_f16((a),(b),(c),0,0,0)

__device__ __forceinline__ h2 pk2(float a, float b) {
  return __builtin_bit_cast(h2, __builtin_amdgcn_cvt_pkrtz(a, b));
}
__device__ __forceinline__ float fexp2(float x) {
#if __has_builtin(__builtin_amdgcn_exp2f)
  return __builtin_amdgcn_exp2f(x);
#else
  return exp2f(x);
#endif
}

#define WT_STRIDE 272   // W^T row stride (136 halves): conflict-free b128
#define KB_STRIDE 144
#define L2E 1.44269504088896f

// R17 = R16 resubmit (R6 bench was an infra flake: "container failed twice",
// no compile/correctness signal; kernel has no spin loops so cannot hang).
// Hardening: __atomic_fetch_add -> atomicAdd (device-scope verified on gfx950).
//
// Structure: merge FUSED into flash via last-block handshake; counters zeroed
// by proj (ws is POISONED each iteration). Saves merge kernel + launch gap.
// R15 counter evidence: whole algorithm = ~8us MFMA-busy + 46MB HBM; our 3
// kernels sum to ~35us of the 110; remainder is harness fill + graph overhead.
//
// Layouts (R13):
//  kswz: slot(mt*2+ks)*1024B + lane*16B : lane(quad,n) = K[kb*16+n][ks*32+quad*8..]
//  vswz (K32 A-frag): slot(hh*4+ut): lane = V^T[16ut+n][tile*64+32hh+8quad+j]
//  q pre-scaled by log2(e) -> scores in log2 domain.

// ---------------- Kernel A: FUSED qkv projection via MFMA ----------------
__global__ __launch_bounds__(256, 2) void proj_mfma(
    const float* __restrict__ x,
    const float* __restrict__ Wq, const float* __restrict__ bq,
    const float* __restrict__ Wk, const float* __restrict__ bk,
    const float* __restrict__ Wv, const float* __restrict__ bv,
    _Float16* __restrict__ qf, _Float16* __restrict__ kswz,
    _Float16* __restrict__ vswz, int* __restrict__ cnt)
{
  const int tid  = threadIdx.x;
  const int lane = tid & 63, wv = tid >> 6;
  const int n = lane & 15, quad = lane >> 4;
  const int r0 = blockIdx.x * 64;

  // zero the merge counters (ws is POISONED by the harness each iteration)
  if (blockIdx.x < 128 && tid == 0) cnt[blockIdx.x] = 0;

  __shared__ __align__(16) char wlds[3][UDIM * WT_STRIDE];   // 52224 B
  __shared__ __align__(16) char kbnc[4 * 16 * KB_STRIDE];    //  9216 B

  #pragma unroll
  for (int p = 0; p < 3; ++p) {
    const float* __restrict__ W = (p == 0) ? Wq : ((p == 1) ? Wk : Wv);
    #pragma unroll
    for (int i = 0; i < 8; ++i) {
      const int idx = i*256 + tid;
      const int nn  = idx & 63;
      const int k4  = (idx >> 6) * 4;
      const float w0 = W[(k4+0)*UDIM + nn];
      const float w1 = W[(k4+1)*UDIM + nn];
      const float w2 = W[(k4+2)*UDIM + nn];
      const float w3 = W[(k4+3)*UDIM + nn];
      int2 wd;
      wd.x = __builtin_bit_cast(int, pk2(w0, w1));
      wd.y = __builtin_bit_cast(int, pk2(w2, w3));
      *(int2*)(wlds[p] + nn*WT_STRIDE + k4*2) = wd;
    }
  }

  const int row = r0 + wv*16 + n;
  h8 xa[4];
  #pragma unroll
  for (int ks = 0; ks < 4; ++ks) {
    const float* xp = x + (size_t)row*DIM + ks*32 + quad*8;
    const f4 a = *(const f4*)xp, b = *(const f4*)(xp + 4);
    int4 pkd;
    pkd.x = __builtin_bit_cast(int, pk2(a[0], a[1]));
    pkd.y = __builtin_bit_cast(int, pk2(a[2], a[3]));
    pkd.z = __builtin_bit_cast(int, pk2(b[0], b[1]));
    pkd.w = __builtin_bit_cast(int, pk2(b[2], b[3]));
    xa[ks] = __builtin_bit_cast(h8, pkd);
  }
  __syncthreads();

  const int b  = r0 / SEQ;
  const int kb = ((r0 % SEQ) >> 4) + wv;
  const int vt = (r0 % SEQ) >> 6;          // 64-key tile index within batch

  #pragma unroll
  for (int p = 0; p < 3; ++p) {
    const float* __restrict__ bias = (p == 0) ? bq : ((p == 1) ? bk : bv);
    f4 acc[4];
    #pragma unroll
    for (int nt = 0; nt < 4; ++nt) acc[nt] = (f4){0.f,0.f,0.f,0.f};
    #pragma unroll
    for (int ks = 0; ks < 4; ++ks)
      #pragma unroll
      for (int nt = 0; nt < 4; ++nt) {
        const h8 wf = *(const h8*)(wlds[p] + (nt*16 + n)*WT_STRIDE + (ks*32 + quad*8)*2);
        acc[nt] = MFMA_K32(xa[ks], wf, acc[nt]);
      }
    #pragma unroll
    for (int nt = 0; nt < 4; ++nt) {
      const float bb = bias[nt*16 + n];
      #pragma unroll
      for (int r = 0; r < 4; ++r) acc[nt][r] += bb;
    }

    if (p == 0) {
      #pragma unroll
      for (int nt = 0; nt < 4; ++nt)
        #pragma unroll
        for (int r = 0; r < 4; ++r) acc[nt][r] *= L2E;
      const int par = lane & 1;
      const unsigned sel = par ? 0x03020706u : 0x05040100u;
      #pragma unroll
      for (int nt = 0; nt < 4; ++nt)
        #pragma unroll
        for (int pp = 0; pp < 2; ++pp) {
          const int r = 2*pp;
          unsigned A  = __builtin_bit_cast(unsigned, pk2(acc[nt][r], acc[nt][r+1]));
          unsigned Bs = (unsigned)__builtin_amdgcn_mov_dpp((int)A, 0xB1, 0xF, 0xF, true);
          unsigned w  = __builtin_amdgcn_perm(Bs, A, sel);
          const int orow = r0 + wv*16 + 4*quad + r + par;
          const int ocol = nt*16 + n - par;
          *(unsigned*)((char*)qf + ((size_t)orow*UDIM + ocol)*2) = w;
        }
    } else if (p == 1) {
      char* base = kbnc + wv*(16*KB_STRIDE);
      #pragma unroll
      for (int nt = 0; nt < 4; ++nt)
        #pragma unroll
        for (int r = 0; r < 4; ++r)
          *(_Float16*)(base + (4*quad + r)*KB_STRIDE + (nt*16 + n)*2) =
              (_Float16)acc[nt][r];
      _Float16* kdst = kswz + (size_t)b*SEQ*UDIM;
      #pragma unroll
      for (int ks = 0; ks < 2; ++ks) {
        const h8 f = *(const h8*)(base + n*KB_STRIDE + ks*64 + quad*16);
        *(h8*)(kdst + ((size_t)(kb*2 + ks)*64 + lane)*8) = f;
      }
    } else {
      // V in K32 A-frag layout.
      _Float16* vdst = vswz + (size_t)b*SEQ*UDIM + (size_t)vt*4096;
      const int hh = wv >> 1;
      const int qp = 2*(wv & 1) + (quad >> 1);
      const int jb = (quad & 1) * 4;
      #pragma unroll
      for (int nt = 0; nt < 4; ++nt) {
        int2 t;
        t.x = __builtin_bit_cast(int, pk2(acc[nt][0], acc[nt][1]));
        t.y = __builtin_bit_cast(int, pk2(acc[nt][2], acc[nt][3]));
        *(int2*)(vdst + (hh*4 + nt)*512 + (16*qp + n)*8 + jb) = t;
      }
    }
  }
}

// ---------------- Kernel B: flash + fused last-block merge ----------------
__global__ __launch_bounds__(256, 3) void flash_attn_t(
    const _Float16* __restrict__ qf, const _Float16* __restrict__ kswz,
    const _Float16* __restrict__ vswz,
    _Float16* __restrict__ opart, float* __restrict__ Mp, float* __restrict__ Lp,
    int* __restrict__ cnt, float* __restrict__ out)
{
  const int qt = blockIdx.x, b = blockIdx.y, sp = blockIdx.z;
  const int ns = gridDim.z;
  const int kt0 = (sp * NT) / ns;
  const int kt1 = ((sp + 1) * NT) / ns;
  const int tid = threadIdx.x;
  const int lane = tid & 63, wid = tid >> 6;
  const int n = lane & 15, quad = lane >> 4;
  const int qbase = qt*128 + wid*32;

  __shared__ int lastflag;

  const _Float16* __restrict__ qb = qf + (size_t)b*SEQ*UDIM;
  const _Float16* kpl = kswz + (size_t)b*SEQ*UDIM + (size_t)kt0*4096 + lane*8;
  const _Float16* kph = kpl + 2048;
  const _Float16* vpl = vswz + (size_t)b*SEQ*UDIM + (size_t)kt0*4096 + lane*8;
  const _Float16* vph = vpl + 2048;

  h8 qB[2][2];
  #pragma unroll
  for (int nt = 0; nt < 2; ++nt)
    #pragma unroll
    for (int ks = 0; ks < 2; ++ks)
      qB[nt][ks] = *(const h8*)(qb + (size_t)(qbase + nt*16 + n)*UDIM + ks*32 + quad*8);

  f4 O[4][2], Ol[2];
  #pragma unroll
  for (int ut = 0; ut < 4; ++ut)
    #pragma unroll
    for (int nt = 0; nt < 2; ++nt) O[ut][nt] = (f4){0.f,0.f,0.f,0.f};
  Ol[0] = (f4){0.f,0.f,0.f,0.f};
  Ol[1] = (f4){0.f,0.f,0.f,0.f};

  float M[2] = {-1e30f, -1e30f};

  h8 ones8;
  { const _Float16 o = (_Float16)1.0f;
    #pragma unroll
    for (int i = 0; i < 8; ++i) ones8[i] = o; }

  const int alo4 = ((32*((lane >> 4) & 1) + (lane & 15)) << 2);
  const int ahi4 = alo4 + 64;
  const bool qlo = (lane < 32);

  h8 ka[4][2];
  ka[0][0] = *(const h8*)(kpl);        ka[0][1] = *(const h8*)(kpl +  512);
  ka[1][0] = *(const h8*)(kpl + 1024); ka[1][1] = *(const h8*)(kpl + 1536);
  ka[2][0] = *(const h8*)(kph);        ka[2][1] = *(const h8*)(kph +  512);
  ka[3][0] = *(const h8*)(kph + 1024); ka[3][1] = *(const h8*)(kph + 1536);

  for (int t = kt0; t < kt1; ++t) {
    h8 va0[4];
    va0[0] = *(const h8*)(vpl);        va0[1] = *(const h8*)(vpl +  512);
    va0[2] = *(const h8*)(vpl + 1024); va0[3] = *(const h8*)(vpl + 1536);

    f4 S[4][2];
    #pragma unroll
    for (int mt = 0; mt < 4; ++mt)
      #pragma unroll
      for (int nt = 0; nt < 2; ++nt) S[mt][nt] = (f4){0.f,0.f,0.f,0.f};
    __builtin_amdgcn_s_setprio(1);
    #pragma unroll
    for (int ks = 0; ks < 2; ++ks)
      #pragma unroll
      for (int mt = 0; mt < 4; ++mt)
        #pragma unroll
        for (int nt = 0; nt < 2; ++nt)
          S[mt][nt] = MFMA_K32(ka[mt][ks], qB[nt][ks], S[mt][nt]);
    __builtin_amdgcn_s_setprio(0);

    if (t + 1 < kt1) {
      kpl += 4096; kph += 4096;
      ka[0][0] = *(const h8*)(kpl);        ka[0][1] = *(const h8*)(kpl +  512);
      ka[1][0] = *(const h8*)(kpl + 1024); ka[1][1] = *(const h8*)(kpl + 1536);
      ka[2][0] = *(const h8*)(kph);        ka[2][1] = *(const h8*)(kph +  512);
      ka[3][0] = *(const h8*)(kph + 1024); ka[3][1] = *(const h8*)(kph + 1536);
    }

    float mn[2];
    #pragma unroll
    for (int nt = 0; nt < 2; ++nt) {
      float m0 = fmaxf(fmaxf(S[0][nt][0], S[0][nt][1]), fmaxf(S[0][nt][2], S[0][nt][3]));
      float m1 = fmaxf(fmaxf(S[1][nt][0], S[1][nt][1]), fmaxf(S[1][nt][2], S[1][nt][3]));
      float m2 = fmaxf(fmaxf(S[2][nt][0], S[2][nt][1]), fmaxf(S[2][nt][2], S[2][nt][3]));
      float m3 = fmaxf(fmaxf(S[3][nt][0], S[3][nt][1]), fmaxf(S[3][nt][2], S[3][nt][3]));
      float rm = fmaxf(fmaxf(m0, m1), fmaxf(m2, m3));
      rm = fmaxf(rm, __shfl_xor(rm, 16));
      rm = fmaxf(rm, __shfl_xor(rm, 32));
      mn[nt] = fmaxf(M[nt], rm);
    }

    const bool nochange = (mn[0] == M[0]) && (mn[1] == M[1]);
    if (!__all(nochange)) {
      #pragma unroll
      for (int nt = 0; nt < 2; ++nt) {
        const float alpha = fexp2(M[nt] - mn[nt]);
        #pragma unroll
        for (int ut = 0; ut < 4; ++ut)
          #pragma unroll
          for (int r = 0; r < 4; ++r) O[ut][nt][r] *= alpha;
        #pragma unroll
        for (int r = 0; r < 4; ++r) Ol[nt][r] *= alpha;
      }
    }
    M[0] = mn[0]; M[1] = mn[1];

    h4 pB[4][2];
    #pragma unroll
    for (int mt = 0; mt < 4; ++mt)
      #pragma unroll
      for (int nt = 0; nt < 2; ++nt) {
        #pragma unroll
        for (int r = 0; r < 4; ++r)
          S[mt][nt][r] = fexp2(S[mt][nt][r] - mn[nt]);
        int2 tt;
        tt.x = __builtin_bit_cast(int, pk2(S[mt][nt][0], S[mt][nt][1]));
        tt.y = __builtin_bit_cast(int, pk2(S[mt][nt][2], S[mt][nt][3]));
        pB[mt][nt] = __builtin_bit_cast(h4, tt);
      }

    h8 pb32a[2];
    #pragma unroll
    for (int nt = 0; nt < 2; ++nt) {
      const int2 X = __builtin_bit_cast(int2, pB[0][nt]);
      const int2 Y = __builtin_bit_cast(int2, pB[1][nt]);
      int4 o;
      { int a0 = __builtin_amdgcn_ds_bpermute(alo4, X.x);
        int b0 = __builtin_amdgcn_ds_bpermute(alo4, Y.x);
        int a1 = __builtin_amdgcn_ds_bpermute(alo4, X.y);
        int b1 = __builtin_amdgcn_ds_bpermute(alo4, Y.y);
        int a2 = __builtin_amdgcn_ds_bpermute(ahi4, X.x);
        int b2 = __builtin_amdgcn_ds_bpermute(ahi4, Y.x);
        int a3 = __builtin_amdgcn_ds_bpermute(ahi4, X.y);
        int b3 = __builtin_amdgcn_ds_bpermute(ahi4, Y.y);
        o.x = qlo ? a0 : b0; o.y = qlo ? a1 : b1;
        o.z = qlo ? a2 : b2; o.w = qlo ? a3 : b3; }
      pb32a[nt] = __builtin_bit_cast(h8, o);
    }

    h8 va1[4];
    va1[0] = *(const h8*)(vph);        va1[1] = *(const h8*)(vph +  512);
    va1[2] = *(const h8*)(vph + 1024); va1[3] = *(const h8*)(vph + 1536);

    __builtin_amdgcn_s_setprio(1);
    #pragma unroll
    for (int ut = 0; ut < 4; ++ut)
      #pragma unroll
      for (int nt = 0; nt < 2; ++nt)
        O[ut][nt] = MFMA_K32(va0[ut], pb32a[nt], O[ut][nt]);
    #pragma unroll
    for (int nt = 0; nt < 2; ++nt)
      Ol[nt] = MFMA_K32(ones8, pb32a[nt], Ol[nt]);
    __builtin_amdgcn_s_setprio(0);

    h8 pb32b[2];
    #pragma unroll
    for (int nt = 0; nt < 2; ++nt) {
      const int2 X = __builtin_bit_cast(int2, pB[2][nt]);
      const int2 Y = __builtin_bit_cast(int2, pB[3][nt]);
      int4 o;
      { int a0 = __builtin_amdgcn_ds_bpermute(alo4, X.x);
        int b0 = __builtin_amdgcn_ds_bpermute(alo4, Y.x);
        int a1 = __builtin_amdgcn_ds_bpermute(alo4, X.y);
        int b1 = __builtin_amdgcn_ds_bpermute(alo4, Y.y);
        int a2 = __builtin_amdgcn_ds_bpermute(ahi4, X.x);
        int b2 = __builtin_amdgcn_ds_bpermute(ahi4, Y.x);
        int a3 = __builtin_amdgcn_ds_bpermute(ahi4, X.y);
        int b3 = __builtin_amdgcn_ds_bpermute(ahi4, Y.y);
        o.x = qlo ? a0 : b0; o.y = qlo ? a1 : b1;
        o.z = qlo ? a2 : b2; o.w = qlo ? a3 : b3; }
      pb32b[nt] = __builtin_bit_cast(h8, o);
    }

    __builtin_amdgcn_s_setprio(1);
    #pragma unroll
    for (int ut = 0; ut < 4; ++ut)
      #pragma unroll
      for (int nt = 0; nt < 2; ++nt)
        O[ut][nt] = MFMA_K32(va1[ut], pb32b[nt], O[ut][nt]);
    #pragma unroll
    for (int nt = 0; nt < 2; ++nt)
      Ol[nt] = MFMA_K32(ones8, pb32b[nt], Ol[nt]);
    __builtin_amdgcn_s_setprio(0);

    vpl += 4096; vph += 4096;
  }

  // ---- epilogue: write partials ----
  const size_t rowg = (size_t)sp*BS + (size_t)b*SEQ + qbase;
  #pragma unroll
  for (int nt = 0; nt < 2; ++nt) {
    char* __restrict__ orow = (char*)(opart + (rowg + nt*16 + n)*UDIM);
    #pragma unroll
    for (int ut = 0; ut < 4; ++ut)
      #pragma unroll
      for (int p = 0; p < 2; ++p)
        *(unsigned*)(orow + (ut*16 + quad*4 + 2*p)*2) =
            __builtin_bit_cast(unsigned, pk2(O[ut][nt][2*p], O[ut][nt][2*p+1]));
    if (quad == 0) {
      Mp[rowg + nt*16 + n] = M[nt];        // log2 domain
      Lp[rowg + nt*16 + n] = Ol[nt][0];
    }
  }

  // ---- fused merge: last block of this (b,qt) group does it ----
  __threadfence();                         // release partials (device scope)
  if (tid == 0) {
    const int old = atomicAdd(&cnt[b*32 + qt], 1);   // device-scope (m20)
    lastflag = (old == ns - 1);
  }
  __syncthreads();
  if (!lastflag) return;
  __threadfence();                         // acquire other blocks' partials

  #pragma unroll
  for (int it = 0; it < 8; ++it) {
    const int task = it*256 + tid;         // 2048 tasks: 128 rows x 16 u4
    const int r    = task >> 4;
    const int u4   = (task & 15) * 4;
    const size_t row = (size_t)b*SEQ + qt*128 + r;
    float Mm = -1e30f;
    for (int s = 0; s < ns; ++s) Mm = fmaxf(Mm, Mp[(size_t)s*BS + row]);
    f4 num = (f4){0.f,0.f,0.f,0.f};
    float den = 0.f;
    for (int s = 0; s < ns; ++s) {
      const float w = fexp2(Mp[(size_t)s*BS + row] - Mm);
      den += w * Lp[(size_t)s*BS + row];
      const h4 op = *(const h4*)(opart + ((size_t)s*BS + row)*UDIM + u4);
      #pragma unroll
      for (int i = 0; i < 4; ++i) num[i] += w * (float)op[i];
    }
    const float dinv = 1.f / den;
    *(f4*)(out + row*UDIM + u4) = num * dinv;
  }
}

extern "C" void kernel_launch(void* const* d_in, const int* in_sizes, int n_in,
                              void* d_out, int out_size, void* d_ws, size_t ws_size,
                              hipStream_t stream) {
  (void)in_sizes; (void)n_in; (void)out_size;
  const float* x  = (const float*)d_in[0];
  const float* Wq = (const float*)d_in[1];
  const float* bq = (const float*)d_in[2];
  const float* Wk = (const float*)d_in[3];
  const float* bk = (const float*)d_in[4];
  const float* Wv = (const float*)d_in[5];
  const float* bv = (const float*)d_in[6];
  float* out = (float*)d_out;

  char* ws = (char*)d_ws;
  const size_t fBytes = (size_t)BS * UDIM * 2;
  auto need = [](int nsp) {
    return (size_t)3*BS*UDIM*2 + (size_t)nsp*BS*4*2 + (size_t)nsp*BS*UDIM*2 + 512;
  };
  int nsplit;
  if      (ws_size >= need(NSPLIT)) nsplit = NSPLIT;
  else if (ws_size >= need(4))      nsplit = 4;
  else if (ws_size >= need(2))      nsplit = 2;
  else                              nsplit = 1;

  _Float16* qf    = (_Float16*)(ws);
  _Float16* kswz  = (_Float16*)(ws + fBytes);
  _Float16* vswz  = (_Float16*)(ws + 2*fBytes);
  float*    Mp    = (float*)(ws + 3*fBytes);
  float*    Lp    = (float*)(ws + 3*fBytes + (size_t)nsplit*BS*4);
  _Float16* opart = (_Float16*)(ws + 3*fBytes + (size_t)nsplit*BS*8);
  int*      cnt   = (int*)(ws + 3*fBytes + (size_t)nsplit*BS*8 + (size_t)nsplit*BS*UDIM*2);

  proj_mfma<<<dim3(BS/64), 256, 0, stream>>>(x, Wq, bq, Wk, bk, Wv, bv,
                                             qf, kswz, vswz, cnt);
  flash_attn_t<<<dim3(SEQ/128, BATCH, nsplit), 256, 0, stream>>>(
      qf, kswz, vswz, opart, Mp, Lp, cnt, out);
}

// Round 8
// 109.743 us; speedup vs baseline: 2.6869x; 2.1209x over previous
//
#include <hip/hip_runtime.h>
#include <hip/hip_fp16.h>
#include <math.h>

#define SEQ   4096
#define DIM   128
#define UDIM  64
#define BATCH 4
#define BS    (BATCH*SEQ)
#define NT    (SEQ/64)   // 64 key tiles
#define NSPLIT 6         // 768 blocks = 3072 waves = exactly one resident pass

typedef _Float16 h8 __attribute__((ext_vector_type(8)));
typedef _Float16 h4 __attribute__((ext_vector_type(4)));
typedef _Float16 h2 __attribute__((ext_vector_type(2)));
typedef float    f4 __attribute__((ext_vector_type(4)));

#define MFMA_K32(a,b,c) __builtin_amdgcn_mfma_f32_16x16x32_f16((a),(b),(c),0,0,0)

__device__ __forceinline__ h2 pk2(float a, float b) {
  return __builtin_bit_cast(h2, __builtin_amdgcn_cvt_pkrtz(a, b));
}
__device__ __forceinline__ float fexp2(float x) {
#if __has_builtin(__builtin_amdgcn_exp2f)
  return __builtin_amdgcn_exp2f(x);
#else
  return exp2f(x);
#endif
}

#define WT_STRIDE 272   // W^T row stride (136 halves): conflict-free b128
#define KB_STRIDE 144
#define L2E 1.44269504088896f

// R18 = exact revert to R13 (109.42us, session best).
// R7 evidence: fusing the merge tail into flash collapsed regalloc
// (VGPR 84, scratch spill, 168us) — same failure as R5's fused kernel
// (VGPR 88). The flash hot loop is on a VGPR knife-edge; do not append
// phases to it. Session totals: fixed harness overhead ~55-75us
// (268MB ws fill @43us + graph/launch), kernels ~35-55us, pipe floor
// ~16us. All six structural levers on flash were null/negative.
//
// Layouts:
//  kswz: slot(mt*2+ks)*1024B + lane*16B : lane(quad,n) = K[kb*16+n][ks*32+quad*8..]
//  vswz (K32 A-frag): slot(hh*4+ut): lane = V^T[16ut+n][tile*64+32hh+8quad+j]
//  q pre-scaled by log2(e) -> scores in log2 domain.

// ---------------- Kernel A: FUSED qkv projection via MFMA ----------------
__global__ __launch_bounds__(256, 2) void proj_mfma(
    const float* __restrict__ x,
    const float* __restrict__ Wq, const float* __restrict__ bq,
    const float* __restrict__ Wk, const float* __restrict__ bk,
    const float* __restrict__ Wv, const float* __restrict__ bv,
    _Float16* __restrict__ qf, _Float16* __restrict__ kswz, _Float16* __restrict__ vswz)
{
  const int tid  = threadIdx.x;
  const int lane = tid & 63, wv = tid >> 6;
  const int n = lane & 15, quad = lane >> 4;
  const int r0 = blockIdx.x * 64;

  __shared__ __align__(16) char wlds[3][UDIM * WT_STRIDE];   // 52224 B
  __shared__ __align__(16) char kbnc[4 * 16 * KB_STRIDE];    //  9216 B

  #pragma unroll
  for (int p = 0; p < 3; ++p) {
    const float* __restrict__ W = (p == 0) ? Wq : ((p == 1) ? Wk : Wv);
    #pragma unroll
    for (int i = 0; i < 8; ++i) {
      const int idx = i*256 + tid;
      const int nn  = idx & 63;
      const int k4  = (idx >> 6) * 4;
      const float w0 = W[(k4+0)*UDIM + nn];
      const float w1 = W[(k4+1)*UDIM + nn];
      const float w2 = W[(k4+2)*UDIM + nn];
      const float w3 = W[(k4+3)*UDIM + nn];
      int2 wd;
      wd.x = __builtin_bit_cast(int, pk2(w0, w1));
      wd.y = __builtin_bit_cast(int, pk2(w2, w3));
      *(int2*)(wlds[p] + nn*WT_STRIDE + k4*2) = wd;
    }
  }

  const int row = r0 + wv*16 + n;
  h8 xa[4];
  #pragma unroll
  for (int ks = 0; ks < 4; ++ks) {
    const float* xp = x + (size_t)row*DIM + ks*32 + quad*8;
    const f4 a = *(const f4*)xp, b = *(const f4*)(xp + 4);
    int4 pkd;
    pkd.x = __builtin_bit_cast(int, pk2(a[0], a[1]));
    pkd.y = __builtin_bit_cast(int, pk2(a[2], a[3]));
    pkd.z = __builtin_bit_cast(int, pk2(b[0], b[1]));
    pkd.w = __builtin_bit_cast(int, pk2(b[2], b[3]));
    xa[ks] = __builtin_bit_cast(h8, pkd);
  }
  __syncthreads();

  const int b  = r0 / SEQ;
  const int kb = ((r0 % SEQ) >> 4) + wv;
  const int vt = (r0 % SEQ) >> 6;          // 64-key tile index within batch

  #pragma unroll
  for (int p = 0; p < 3; ++p) {
    const float* __restrict__ bias = (p == 0) ? bq : ((p == 1) ? bk : bv);
    f4 acc[4];
    #pragma unroll
    for (int nt = 0; nt < 4; ++nt) acc[nt] = (f4){0.f,0.f,0.f,0.f};
    #pragma unroll
    for (int ks = 0; ks < 4; ++ks)
      #pragma unroll
      for (int nt = 0; nt < 4; ++nt) {
        const h8 wf = *(const h8*)(wlds[p] + (nt*16 + n)*WT_STRIDE + (ks*32 + quad*8)*2);
        acc[nt] = MFMA_K32(xa[ks], wf, acc[nt]);
      }
    #pragma unroll
    for (int nt = 0; nt < 4; ++nt) {
      const float bb = bias[nt*16 + n];
      #pragma unroll
      for (int r = 0; r < 4; ++r) acc[nt][r] += bb;
    }

    if (p == 0) {
      #pragma unroll
      for (int nt = 0; nt < 4; ++nt)
        #pragma unroll
        for (int r = 0; r < 4; ++r) acc[nt][r] *= L2E;
      const int par = lane & 1;
      const unsigned sel = par ? 0x03020706u : 0x05040100u;
      #pragma unroll
      for (int nt = 0; nt < 4; ++nt)
        #pragma unroll
        for (int pp = 0; pp < 2; ++pp) {
          const int r = 2*pp;
          unsigned A  = __builtin_bit_cast(unsigned, pk2(acc[nt][r], acc[nt][r+1]));
          unsigned Bs = (unsigned)__builtin_amdgcn_mov_dpp((int)A, 0xB1, 0xF, 0xF, true);
          unsigned w  = __builtin_amdgcn_perm(Bs, A, sel);
          const int orow = r0 + wv*16 + 4*quad + r + par;
          const int ocol = nt*16 + n - par;
          *(unsigned*)((char*)qf + ((size_t)orow*UDIM + ocol)*2) = w;
        }
    } else if (p == 1) {
      char* base = kbnc + wv*(16*KB_STRIDE);
      #pragma unroll
      for (int nt = 0; nt < 4; ++nt)
        #pragma unroll
        for (int r = 0; r < 4; ++r)
          *(_Float16*)(base + (4*quad + r)*KB_STRIDE + (nt*16 + n)*2) =
              (_Float16)acc[nt][r];
      _Float16* kdst = kswz + (size_t)b*SEQ*UDIM;
      #pragma unroll
      for (int ks = 0; ks < 2; ++ks) {
        const h8 f = *(const h8*)(base + n*KB_STRIDE + ks*64 + quad*16);
        *(h8*)(kdst + ((size_t)(kb*2 + ks)*64 + lane)*8) = f;
      }
    } else {
      // V in K32 A-frag layout.
      // lane holds V[key=16wv+4quad+r][u=16nt+n]; key_in_tile = 32hh+8quad'+j
      // with hh=wv>>1, quad'=2*(wv&1)+(quad>>1), j=4*(quad&1)+r.
      _Float16* vdst = vswz + (size_t)b*SEQ*UDIM + (size_t)vt*4096;
      const int hh = wv >> 1;
      const int qp = 2*(wv & 1) + (quad >> 1);
      const int jb = (quad & 1) * 4;
      #pragma unroll
      for (int nt = 0; nt < 4; ++nt) {
        int2 t;
        t.x = __builtin_bit_cast(int, pk2(acc[nt][0], acc[nt][1]));
        t.y = __builtin_bit_cast(int, pk2(acc[nt][2], acc[nt][3]));
        *(int2*)(vdst + (hh*4 + nt)*512 + (16*qp + n)*8 + jb) = t;
      }
    }
  }
}

// ---------------- Kernel B: barrier-free flash (K32 PV) ----------------
// PV uses mfma_16x16x32 (full-K): 16 QK + 16 PV + 4 Ol = 36 MFMA slots per
// wave-tile. P repacked from QK C-layout to K32 B-frag layout via
// 8 ds_bpermute + 4 selects per (hh,nt).
__global__ __launch_bounds__(256, 3) void flash_attn_t(
    const _Float16* __restrict__ qf, const _Float16* __restrict__ kswz,
    const _Float16* __restrict__ vswz,
    _Float16* __restrict__ opart, float* __restrict__ Mp, float* __restrict__ Lp)
{
  const int qt = blockIdx.x, b = blockIdx.y, sp = blockIdx.z;
  const int ns = gridDim.z;
  const int kt0 = (sp * NT) / ns;
  const int kt1 = ((sp + 1) * NT) / ns;
  const int tid = threadIdx.x;
  const int lane = tid & 63, wid = tid >> 6;
  const int n = lane & 15, quad = lane >> 4;
  const int qbase = qt*128 + wid*32;

  const _Float16* __restrict__ qb = qf + (size_t)b*SEQ*UDIM;
  const _Float16* kpl = kswz + (size_t)b*SEQ*UDIM + (size_t)kt0*4096 + lane*8;
  const _Float16* kph = kpl + 2048;
  const _Float16* vpl = vswz + (size_t)b*SEQ*UDIM + (size_t)kt0*4096 + lane*8;
  const _Float16* vph = vpl + 2048;

  h8 qB[2][2];
  #pragma unroll
  for (int nt = 0; nt < 2; ++nt)
    #pragma unroll
    for (int ks = 0; ks < 2; ++ks)
      qB[nt][ks] = *(const h8*)(qb + (size_t)(qbase + nt*16 + n)*UDIM + ks*32 + quad*8);

  f4 O[4][2], Ol[2];
  #pragma unroll
  for (int ut = 0; ut < 4; ++ut)
    #pragma unroll
    for (int nt = 0; nt < 2; ++nt) O[ut][nt] = (f4){0.f,0.f,0.f,0.f};
  Ol[0] = (f4){0.f,0.f,0.f,0.f};
  Ol[1] = (f4){0.f,0.f,0.f,0.f};

  float M[2] = {-1e30f, -1e30f};

  h8 ones8;
  { const _Float16 o = (_Float16)1.0f;
    #pragma unroll
    for (int i = 0; i < 8; ++i) ones8[i] = o; }

  // repack gather addresses (bytes): lo from lane 32*(quad&1)+n, hi = +16
  const int alo4 = ((32*((lane >> 4) & 1) + (lane & 15)) << 2);
  const int ahi4 = alo4 + 64;
  const bool qlo = (lane < 32);

  // ---- prime K for first tile ----
  h8 ka[4][2];
  ka[0][0] = *(const h8*)(kpl);        ka[0][1] = *(const h8*)(kpl +  512);
  ka[1][0] = *(const h8*)(kpl + 1024); ka[1][1] = *(const h8*)(kpl + 1536);
  ka[2][0] = *(const h8*)(kph);        ka[2][1] = *(const h8*)(kph +  512);
  ka[3][0] = *(const h8*)(kph + 1024); ka[3][1] = *(const h8*)(kph + 1536);

  for (int t = kt0; t < kt1; ++t) {
    // ---- V hh=0 loads: issue now, consumed after softmax ----
    h8 va0[4];
    va0[0] = *(const h8*)(vpl);        va0[1] = *(const h8*)(vpl +  512);
    va0[2] = *(const h8*)(vpl + 1024); va0[3] = *(const h8*)(vpl + 1536);

    // ---- S^T = K·Q^T (log2 domain: q pre-scaled) ----
    f4 S[4][2];
    #pragma unroll
    for (int mt = 0; mt < 4; ++mt)
      #pragma unroll
      for (int nt = 0; nt < 2; ++nt) S[mt][nt] = (f4){0.f,0.f,0.f,0.f};
    #pragma unroll
    for (int ks = 0; ks < 2; ++ks)
      #pragma unroll
      for (int mt = 0; mt < 4; ++mt)
        #pragma unroll
        for (int nt = 0; nt < 2; ++nt)
          S[mt][nt] = MFMA_K32(ka[mt][ks], qB[nt][ks], S[mt][nt]);

    // ---- prefetch next tile's K in place (consumed next iter) ----
    if (t + 1 < kt1) {
      kpl += 4096; kph += 4096;
      ka[0][0] = *(const h8*)(kpl);        ka[0][1] = *(const h8*)(kpl +  512);
      ka[1][0] = *(const h8*)(kpl + 1024); ka[1][1] = *(const h8*)(kpl + 1536);
      ka[2][0] = *(const h8*)(kph);        ka[2][1] = *(const h8*)(kph +  512);
      ka[3][0] = *(const h8*)(kph + 1024); ka[3][1] = *(const h8*)(kph + 1536);
    }

    // ---- row max: tree + 2 shuffles ----
    float mn[2];
    #pragma unroll
    for (int nt = 0; nt < 2; ++nt) {
      float m0 = fmaxf(fmaxf(S[0][nt][0], S[0][nt][1]), fmaxf(S[0][nt][2], S[0][nt][3]));
      float m1 = fmaxf(fmaxf(S[1][nt][0], S[1][nt][1]), fmaxf(S[1][nt][2], S[1][nt][3]));
      float m2 = fmaxf(fmaxf(S[2][nt][0], S[2][nt][1]), fmaxf(S[2][nt][2], S[2][nt][3]));
      float m3 = fmaxf(fmaxf(S[3][nt][0], S[3][nt][1]), fmaxf(S[3][nt][2], S[3][nt][3]));
      float rm = fmaxf(fmaxf(m0, m1), fmaxf(m2, m3));
      rm = fmaxf(rm, __shfl_xor(rm, 16));
      rm = fmaxf(rm, __shfl_xor(rm, 32));
      mn[nt] = fmaxf(M[nt], rm);
    }

    // ---- rescale O only if some lane's max moved ----
    const bool nochange = (mn[0] == M[0]) && (mn[1] == M[1]);
    if (!__all(nochange)) {
      #pragma unroll
      for (int nt = 0; nt < 2; ++nt) {
        const float alpha = fexp2(M[nt] - mn[nt]);
        #pragma unroll
        for (int ut = 0; ut < 4; ++ut)
          #pragma unroll
          for (int r = 0; r < 4; ++r) O[ut][nt][r] *= alpha;
        #pragma unroll
        for (int r = 0; r < 4; ++r) Ol[nt][r] *= alpha;
      }
    }
    M[0] = mn[0]; M[1] = mn[1];

    // ---- P = exp2(S - m); pack to h4 (QK C-layout) ----
    h4 pB[4][2];
    #pragma unroll
    for (int mt = 0; mt < 4; ++mt)
      #pragma unroll
      for (int nt = 0; nt < 2; ++nt) {
        #pragma unroll
        for (int r = 0; r < 4; ++r)
          S[mt][nt][r] = fexp2(S[mt][nt][r] - mn[nt]);
        int2 tt;
        tt.x = __builtin_bit_cast(int, pk2(S[mt][nt][0], S[mt][nt][1]));
        tt.y = __builtin_bit_cast(int, pk2(S[mt][nt][2], S[mt][nt][3]));
        pB[mt][nt] = __builtin_bit_cast(h4, tt);
      }

    // ---- repack hh=0 (keys 0..31): pB[0],pB[1] -> K32 B-frags ----
    h8 pb32a[2];
    #pragma unroll
    for (int nt = 0; nt < 2; ++nt) {
      const int2 X = __builtin_bit_cast(int2, pB[0][nt]);
      const int2 Y = __builtin_bit_cast(int2, pB[1][nt]);
      int4 o;
      { int a0 = __builtin_amdgcn_ds_bpermute(alo4, X.x);
        int b0 = __builtin_amdgcn_ds_bpermute(alo4, Y.x);
        int a1 = __builtin_amdgcn_ds_bpermute(alo4, X.y);
        int b1 = __builtin_amdgcn_ds_bpermute(alo4, Y.y);
        int a2 = __builtin_amdgcn_ds_bpermute(ahi4, X.x);
        int b2 = __builtin_amdgcn_ds_bpermute(ahi4, Y.x);
        int a3 = __builtin_amdgcn_ds_bpermute(ahi4, X.y);
        int b3 = __builtin_amdgcn_ds_bpermute(ahi4, Y.y);
        o.x = qlo ? a0 : b0; o.y = qlo ? a1 : b1;
        o.z = qlo ? a2 : b2; o.w = qlo ? a3 : b3; }
      pb32a[nt] = __builtin_bit_cast(h8, o);
    }

    // ---- issue V hh=1 loads (covered by hh=0 MFMAs + hh=1 repack) ----
    h8 va1[4];
    va1[0] = *(const h8*)(vph);        va1[1] = *(const h8*)(vph +  512);
    va1[2] = *(const h8*)(vph + 1024); va1[3] = *(const h8*)(vph + 1536);

    // ---- PV hh=0 ----
    #pragma unroll
    for (int ut = 0; ut < 4; ++ut)
      #pragma unroll
      for (int nt = 0; nt < 2; ++nt)
        O[ut][nt] = MFMA_K32(va0[ut], pb32a[nt], O[ut][nt]);
    #pragma unroll
    for (int nt = 0; nt < 2; ++nt)
      Ol[nt] = MFMA_K32(ones8, pb32a[nt], Ol[nt]);

    // ---- repack hh=1 (keys 32..63): pB[2],pB[3] ----
    h8 pb32b[2];
    #pragma unroll
    for (int nt = 0; nt < 2; ++nt) {
      const int2 X = __builtin_bit_cast(int2, pB[2][nt]);
      const int2 Y = __builtin_bit_cast(int2, pB[3][nt]);
      int4 o;
      { int a0 = __builtin_amdgcn_ds_bpermute(alo4, X.x);
        int b0 = __builtin_amdgcn_ds_bpermute(alo4, Y.x);
        int a1 = __builtin_amdgcn_ds_bpermute(alo4, X.y);
        int b1 = __builtin_amdgcn_ds_bpermute(alo4, Y.y);
        int a2 = __builtin_amdgcn_ds_bpermute(ahi4, X.x);
        int b2 = __builtin_amdgcn_ds_bpermute(ahi4, Y.x);
        int a3 = __builtin_amdgcn_ds_bpermute(ahi4, X.y);
        int b3 = __builtin_amdgcn_ds_bpermute(ahi4, Y.y);
        o.x = qlo ? a0 : b0; o.y = qlo ? a1 : b1;
        o.z = qlo ? a2 : b2; o.w = qlo ? a3 : b3; }
      pb32b[nt] = __builtin_bit_cast(h8, o);
    }

    // ---- PV hh=1 ----
    #pragma unroll
    for (int ut = 0; ut < 4; ++ut)
      #pragma unroll
      for (int nt = 0; nt < 2; ++nt)
        O[ut][nt] = MFMA_K32(va1[ut], pb32b[nt], O[ut][nt]);
    #pragma unroll
    for (int nt = 0; nt < 2; ++nt)
      Ol[nt] = MFMA_K32(ones8, pb32b[nt], Ol[nt]);

    vpl += 4096; vph += 4096;
  }

  // ---- epilogue ----
  const size_t rowg = (size_t)sp*BS + (size_t)b*SEQ + qbase;
  #pragma unroll
  for (int nt = 0; nt < 2; ++nt) {
    char* __restrict__ orow = (char*)(opart + (rowg + nt*16 + n)*UDIM);
    #pragma unroll
    for (int ut = 0; ut < 4; ++ut)
      #pragma unroll
      for (int p = 0; p < 2; ++p)
        *(unsigned*)(orow + (ut*16 + quad*4 + 2*p)*2) =
            __builtin_bit_cast(unsigned, pk2(O[ut][nt][2*p], O[ut][nt][2*p+1]));
    if (quad == 0) {
      Mp[rowg + nt*16 + n] = M[nt];        // log2 domain
      Lp[rowg + nt*16 + n] = Ol[nt][0];
    }
  }
}

// ---------------- Kernel C: merge key-split partials ----------------
__global__ __launch_bounds__(256) void merge_out(
    const _Float16* __restrict__ opart, const float* __restrict__ Mp,
    const float* __restrict__ Lp, float* __restrict__ out, int nsplit)
{
  const int tid = threadIdx.x;
  const int row = blockIdx.x*16 + (tid >> 4);
  const int u4  = (tid & 15) * 4;
  float M = -1e30f;
  for (int s = 0; s < nsplit; ++s) M = fmaxf(M, Mp[(size_t)s*BS + row]);
  f4 num = (f4){0.f,0.f,0.f,0.f};
  float den = 0.f;
  for (int s = 0; s < nsplit; ++s) {
    const float w = fexp2(Mp[(size_t)s*BS + row] - M);
    den += w * Lp[(size_t)s*BS + row];
    const h4 op = *(const h4*)(opart + ((size_t)s*BS + row)*UDIM + u4);
    #pragma unroll
    for (int i = 0; i < 4; ++i) num[i] += w * (float)op[i];
  }
  const float dinv = 1.f / den;
  *(f4*)(out + (size_t)row*UDIM + u4) = num * dinv;
}

extern "C" void kernel_launch(void* const* d_in, const int* in_sizes, int n_in,
                              void* d_out, int out_size, void* d_ws, size_t ws_size,
                              hipStream_t stream) {
  (void)in_sizes; (void)n_in; (void)out_size;
  const float* x  = (const float*)d_in[0];
  const float* Wq = (const float*)d_in[1];
  const float* bq = (const float*)d_in[2];
  const float* Wk = (const float*)d_in[3];
  const float* bk = (const float*)d_in[4];
  const float* Wv = (const float*)d_in[5];
  const float* bv = (const float*)d_in[6];
  float* out = (float*)d_out;

  char* ws = (char*)d_ws;
  const size_t fBytes = (size_t)BS * UDIM * 2;
  auto need = [](int nsp) {
    return (size_t)3*BS*UDIM*2 + (size_t)nsp*BS*4*2 + (size_t)nsp*BS*UDIM*2;
  };
  int nsplit;
  if      (ws_size >= need(NSPLIT)) nsplit = NSPLIT;
  else if (ws_size >= need(4))      nsplit = 4;
  else if (ws_size >= need(2))      nsplit = 2;
  else                              nsplit = 1;

  _Float16* qf   = (_Float16*)(ws);
  _Float16* kswz = (_Float16*)(ws + fBytes);
  _Float16* vswz = (_Float16*)(ws + 2*fBytes);
  float* Mp      = (float*)(ws + 3*fBytes);
  float* Lp      = (float*)(ws + 3*fBytes + (size_t)nsplit*BS*4);
  _Float16* opart = (_Float16*)(ws + 3*fBytes + (size_t)nsplit*BS*8);

  proj_mfma<<<dim3(BS/64), 256, 0, stream>>>(x, Wq, bq, Wk, bk, Wv, bv, qf, kswz, vswz);
  flash_attn_t<<<dim3(SEQ/128, BATCH, nsplit), 256, 0, stream>>>(
      qf, kswz, vswz, opart, Mp, Lp);
  merge_out<<<dim3(BS/16), 256, 0, stream>>>(opart, Mp, Lp, out, nsplit);
}